// Round 11
// baseline (3821.848 us; speedup 1.0000x reference)
//
#include <hip/hip_runtime.h>
#include <hip/hip_bf16.h>

#define N_OUT 25
#define BOS   4093

typedef __attribute__((ext_vector_type(8))) short bf16x8;
typedef __attribute__((ext_vector_type(4))) float f32x4;

__device__ inline unsigned short f2bf(float f) {
    unsigned int u = __builtin_bit_cast(unsigned int, f);
    unsigned int r = (u + 0x7fffu + ((u >> 16) & 1u)) >> 16;
    return (unsigned short)r;
}
__device__ inline float bf2f(unsigned short s) {
    return __builtin_bit_cast(float, (unsigned int)s << 16);
}
__device__ inline float sigf(float x) { return 1.f / (1.f + expf(-x)); }

// ---------------------------------------------------------------------------
// Agent-scope (sc1) helpers — proven R5-R10.
// ---------------------------------------------------------------------------
__device__ __forceinline__ unsigned long long ld_u64_coh(const void* p) {
    return __hip_atomic_load((const unsigned long long*)p, __ATOMIC_RELAXED, __HIP_MEMORY_SCOPE_AGENT);
}
__device__ __forceinline__ void st_u64_coh(void* p, unsigned long long v) {
    __hip_atomic_store((unsigned long long*)p, v, __ATOMIC_RELAXED, __HIP_MEMORY_SCOPE_AGENT);
}
__device__ __forceinline__ void st_u32_coh(void* p, unsigned int v) {
    __hip_atomic_store((unsigned int*)p, v, __ATOMIC_RELAXED, __HIP_MEMORY_SCOPE_AGENT);
}
__device__ __forceinline__ unsigned short ld_u16_coh(const unsigned short* p) {
    return __hip_atomic_load(p, __ATOMIC_RELAXED, __HIP_MEMORY_SCOPE_AGENT);
}
__device__ __forceinline__ int ld_i32_coh(const int* p) {
    return __hip_atomic_load(p, __ATOMIC_RELAXED, __HIP_MEMORY_SCOPE_AGENT);
}
__device__ __forceinline__ void st_i32_coh(int* p, int v) {
    __hip_atomic_store(p, v, __ATOMIC_RELAXED, __HIP_MEMORY_SCOPE_AGENT);
}
__device__ inline unsigned long long pack_ff(float a, float b) {
    return ((unsigned long long)__builtin_bit_cast(unsigned int, b) << 32) |
           __builtin_bit_cast(unsigned int, a);
}
__device__ inline unsigned long long pack_if(int a, float b) {
    return ((unsigned long long)__builtin_bit_cast(unsigned int, b) << 32) |
           (unsigned int)a;
}
__device__ __forceinline__ void spin_ge(const int* p, int tgt)
{
    while (ld_i32_coh(p) < tgt) __builtin_amdgcn_s_sleep(1);
}

// Wide sc1 load (16B)
__device__ __forceinline__ bf16x8 ld_bf8_sc1(const unsigned short* p) {
    bf16x8 r;
    asm volatile("global_load_dwordx4 %0, %1, off sc1" : "=v"(r) : "v"(p));
    return r;
}
#define VM_FENCE do { asm volatile("s_waitcnt vmcnt(0)" ::: "memory"); \
                      __builtin_amdgcn_sched_barrier(0); } while (0)

// ---------------------------------------------------------------------------
// bf16 MFMA GEMM: C = act(A @ W^T + bias)
// ---------------------------------------------------------------------------
template<int AFP32, int OUT_BF, int ACT>
__global__ __launch_bounds__(256)
void gemm_mfma(const void* __restrict__ Ap, int lda,
               const unsigned short* __restrict__ W, int ldw,
               const float* __restrict__ bias,
               void* __restrict__ Cp, int ldc, int K)
{
    __shared__ short Abuf[128 * 32];
    __shared__ short Wbuf[128 * 32];
    const int tid  = threadIdx.x;
    const int lane = tid & 63;
    const int wave = tid >> 6;
    const int wr = wave >> 1, wc = wave & 1;
    const int l15 = lane & 15, kg = lane >> 4;
    const int m0 = blockIdx.y * 128, n0 = blockIdx.x * 128;

    const float* Af = (const float*)Ap;
    const unsigned short* Ab = (const unsigned short*)Ap;

    f32x4 acc[4][4];
#pragma unroll
    for (int i = 0; i < 4; ++i)
#pragma unroll
        for (int j = 0; j < 4; ++j) acc[i][j] = f32x4{0.f, 0.f, 0.f, 0.f};

    const bf16x8* Av = (const bf16x8*)Abuf;
    const bf16x8* Wv = (const bf16x8*)Wbuf;

    for (int k0 = 0; k0 < K; k0 += 32) {
#pragma unroll
        for (int cc = 0; cc < 2; ++cc) {
            int c = tid + cc * 256;
            int row = c >> 2, k8 = (c & 3) * 8;
            if (AFP32) {
                const float* src = &Af[(size_t)(m0 + row) * lda + k0 + k8];
                float4 v0 = *reinterpret_cast<const float4*>(src);
                float4 v1 = *reinterpret_cast<const float4*>(src + 4);
                bf16x8 s;
                s[0] = (short)f2bf(v0.x); s[1] = (short)f2bf(v0.y);
                s[2] = (short)f2bf(v0.z); s[3] = (short)f2bf(v0.w);
                s[4] = (short)f2bf(v1.x); s[5] = (short)f2bf(v1.y);
                s[6] = (short)f2bf(v1.z); s[7] = (short)f2bf(v1.w);
                *reinterpret_cast<bf16x8*>(&Abuf[row * 32 + k8]) = s;
            } else {
                *reinterpret_cast<bf16x8*>(&Abuf[row * 32 + k8]) =
                    *reinterpret_cast<const bf16x8*>(&Ab[(size_t)(m0 + row) * lda + k0 + k8]);
            }
            *reinterpret_cast<bf16x8*>(&Wbuf[row * 32 + k8]) =
                *reinterpret_cast<const bf16x8*>(&W[(size_t)(n0 + row) * ldw + k0 + k8]);
        }
        __syncthreads();
        bf16x8 a[4], b[4];
#pragma unroll
        for (int i = 0; i < 4; ++i) a[i] = Av[(wr * 64 + i * 16 + l15) * 4 + kg];
#pragma unroll
        for (int j = 0; j < 4; ++j) b[j] = Wv[(wc * 64 + j * 16 + l15) * 4 + kg];
#pragma unroll
        for (int i = 0; i < 4; ++i)
#pragma unroll
            for (int j = 0; j < 4; ++j)
                acc[i][j] = __builtin_amdgcn_mfma_f32_16x16x32_bf16(a[i], b[j], acc[i][j], 0, 0, 0);
        __syncthreads();
    }

    float* Cf = (float*)Cp;
    unsigned short* Cb = (unsigned short*)Cp;
#pragma unroll
    for (int i = 0; i < 4; ++i) {
#pragma unroll
        for (int j = 0; j < 4; ++j) {
            int n = n0 + wc * 64 + j * 16 + l15;
            float bv = bias[n];
#pragma unroll
            for (int r = 0; r < 4; ++r) {
                int m = m0 + wr * 64 + i * 16 + kg * 4 + r;
                float v = acc[i][j][r] + bv;
                if (ACT == 1) v = v > 0.f ? v : 0.01f * v;
                if (OUT_BF) Cb[(size_t)m * ldc + n] = f2bf(v);
                else        Cf[(size_t)m * ldc + n] = v;
            }
        }
    }
}

// ---------------------------------------------------------------------------
// Persistent recurrence, row-partitioned (R=8 x C=4 per chain, 64 WGs):
// WG (r,c) owns rows r*16..r*16+15, h-cols c*128..c*128+127.
// A-panel (16 rows x 512 cols) staged in LDS once per step (1024 sc1
// requests, 4x fewer than R10); waves share A via ds_read.
// ---------------------------------------------------------------------------
__global__ __launch_bounds__(256, 1)
void recur_persist(const unsigned short* __restrict__ enc_gi_bf,
                   const float* __restrict__ enc_bih, const float* __restrict__ enc_bhh,
                   const unsigned short* __restrict__ encwhh_bf,
                   const unsigned short* __restrict__ decwih_bf,
                   const unsigned short* __restrict__ decwhh_bf,
                   const float* __restrict__ dec_bih, const float* __restrict__ dec_bhh,
                   unsigned short* __restrict__ encout_bf,
                   unsigned short* __restrict__ hDb,
                   int* efl, int* dfl)
{
    __shared__ unsigned short hA[16 * 520];   // A panel (padded: 520 u16/row)
    __shared__ unsigned short hB[16 * 520];   // dec1 second panel
    __shared__ unsigned short tp[16 * 132];   // output pack tile (padded)

    const int g = blockIdx.x;                 // 0..63
    const int tid = threadIdx.x, w = tid >> 6, lane = tid & 63;
    const int l15 = lane & 15, kg = lane >> 4;
    const int srow = tid >> 4, sseg = tid & 15;   // staging: row, 32-col segment

    if (g < 32) {
        // ============================ ENCODER ============================
        const int r = g >> 2, c = g & 3;
        const int R0 = r * 16;
        const int hc0 = c * 128 + w * 32;
        int wrow[6];
#pragma unroll
        for (int a = 0; a < 6; ++a) wrow[a] = (a >> 1) * 512 + hc0 + (a & 1) * 16 + l15;
        float hreg[2][4] = {{0.f,0.f,0.f,0.f},{0.f,0.f,0.f,0.f}};

        for (int i = 0; i < 105; ++i) {
            f32x4 acc[6];
#pragma unroll
            for (int a = 0; a < 6; ++a) acc[a] = f32x4{0.f,0.f,0.f,0.f};

            if (i > 0) {
                if (tid < 4) spin_ge(&efl[(r * 4 + tid) * 32], i);
                __syncthreads();
                asm volatile("" ::: "memory");
                // stage A panel: 16 rows x 512 cols, 64B per thread
                const unsigned short* src = encout_bf + (size_t)(i - 1) * 65536
                                          + (size_t)(R0 + srow) * 512 + sseg * 32;
                bf16x8 ld[4];
                VM_FENCE;
#pragma unroll
                for (int k = 0; k < 4; ++k) ld[k] = ld_bf8_sc1(src + k * 8);
                VM_FENCE;
#pragma unroll
                for (int k = 0; k < 4; ++k)
                    *(bf16x8*)&hA[srow * 520 + sseg * 32 + k * 8] = ld[k];
                __syncthreads();
#pragma unroll
                for (int ks = 0; ks < 16; ++ks) {
                    bf16x8 a = *(const bf16x8*)&hA[l15 * 520 + ks * 32 + kg * 8];
#pragma unroll
                    for (int t = 0; t < 6; ++t) {
                        bf16x8 bv = *(const bf16x8*)&encwhh_bf[(size_t)wrow[t] * 512 + ks * 32 + kg * 8];
                        acc[t] = __builtin_amdgcn_mfma_f32_16x16x32_bf16(a, bv, acc[t], 0, 0, 0);
                    }
                }
                __syncthreads();               // hA reuse guard (next write)
            }
#pragma unroll
            for (int ct = 0; ct < 2; ++ct) {
                int jc = hc0 + ct * 16 + l15;
                float bhr = enc_bhh[jc], bhz = enc_bhh[512 + jc], bhn = enc_bhh[1024 + jc];
#pragma unroll
                for (int rr = 0; rr < 4; ++rr) {
                    int br = R0 + kg * 4 + rr;
                    float gr_, gz_, gn_;
                    if (i < 80) {
                        const unsigned short* gp = enc_gi_bf + ((size_t)i * 128 + br) * 1536 + jc;
                        gr_ = bf2f(gp[0]); gz_ = bf2f(gp[512]); gn_ = bf2f(gp[1024]);
                    } else {
                        gr_ = enc_bih[jc]; gz_ = enc_bih[512 + jc]; gn_ = enc_bih[1024 + jc];
                    }
                    float rv = sigf(gr_ + bhr + acc[ct][rr]);
                    float zv = sigf(gz_ + bhz + acc[2 + ct][rr]);
                    float nv = tanhf(gn_ + rv * (acc[4 + ct][rr] + bhn));
                    float v = (1.f - zv) * nv + zv * hreg[ct][rr];
                    hreg[ct][rr] = v;
                    tp[(kg * 4 + rr) * 132 + w * 32 + ct * 16 + l15] = f2bf(v);
                }
            }
            __syncthreads();
            // cooperative store: 16 rows x 128 cols = 512 u64, 2 per thread
#pragma unroll
            for (int rep = 0; rep < 2; ++rep) {
                int idx = tid + rep * 256;
                int row = idx >> 5, q = idx & 31;
                unsigned long long v = *(const unsigned long long*)&tp[row * 132 + q * 4];
                st_u64_coh(&encout_bf[(size_t)i * 65536 + (size_t)(R0 + row) * 512 + c * 128 + q * 4], v);
            }
            __syncthreads();                   // drain sc1 stores
            if (tid == 0) st_i32_coh(&efl[g * 32], i + 1);
        }
    } else {
        // ============================== DEC1 ==============================
        const int g2 = g - 32;
        const int r = g2 >> 2, c = g2 & 3;
        const int R0 = r * 16;
        const int hc0 = c * 128 + w * 32;
        int wrow[6];
#pragma unroll
        for (int a = 0; a < 6; ++a) wrow[a] = (a >> 1) * 512 + hc0 + (a & 1) * 16 + l15;
        float hreg[2][4] = {{0.f,0.f,0.f,0.f},{0.f,0.f,0.f,0.f}};

        for (int i = 1; i <= 80; ++i) {
            if (tid < 4) spin_ge(&efl[(r * 4 + tid) * 32], i);
            else if (tid >= 4 && tid < 8 && i >= 2) spin_ge(&dfl[(r * 4 + tid - 4) * 32], i - 1);
            __syncthreads();
            asm volatile("" ::: "memory");

            // stage enc panel (and own-h panel when i>=2) in one burst
            bf16x8 ldA[4], ldB[4];
            const unsigned short* srcA = encout_bf + (size_t)(i - 1) * 65536
                                       + (size_t)(R0 + srow) * 512 + sseg * 32;
            VM_FENCE;
#pragma unroll
            for (int k = 0; k < 4; ++k) ldA[k] = ld_bf8_sc1(srcA + k * 8);
            if (i >= 2) {
                const unsigned short* srcB = hDb + (size_t)((i - 1) & 1) * 65536
                                           + (size_t)(R0 + srow) * 512 + sseg * 32;
#pragma unroll
                for (int k = 0; k < 4; ++k) ldB[k] = ld_bf8_sc1(srcB + k * 8);
            }
            VM_FENCE;
#pragma unroll
            for (int k = 0; k < 4; ++k)
                *(bf16x8*)&hA[srow * 520 + sseg * 32 + k * 8] = ldA[k];
            if (i >= 2) {
#pragma unroll
                for (int k = 0; k < 4; ++k)
                    *(bf16x8*)&hB[srow * 520 + sseg * 32 + k * 8] = ldB[k];
            }
            __syncthreads();

            f32x4 agi[6], agh[6];
#pragma unroll
            for (int t = 0; t < 6; ++t) { agi[t] = f32x4{0.f,0.f,0.f,0.f}; agh[t] = f32x4{0.f,0.f,0.f,0.f}; }
#pragma unroll
            for (int ks = 0; ks < 16; ++ks) {
                bf16x8 a = *(const bf16x8*)&hA[l15 * 520 + ks * 32 + kg * 8];
#pragma unroll
                for (int t = 0; t < 6; ++t) {
                    bf16x8 bv = *(const bf16x8*)&decwih_bf[(size_t)wrow[t] * 1536 + 1024 + ks * 32 + kg * 8];
                    agi[t] = __builtin_amdgcn_mfma_f32_16x16x32_bf16(a, bv, agi[t], 0, 0, 0);
                }
            }
            if (i >= 2) {
#pragma unroll
                for (int ks = 0; ks < 16; ++ks) {
                    bf16x8 a = *(const bf16x8*)&hB[l15 * 520 + ks * 32 + kg * 8];
#pragma unroll
                    for (int t = 0; t < 6; ++t) {
                        bf16x8 bv = *(const bf16x8*)&decwhh_bf[(size_t)wrow[t] * 512 + ks * 32 + kg * 8];
                        agh[t] = __builtin_amdgcn_mfma_f32_16x16x32_bf16(a, bv, agh[t], 0, 0, 0);
                    }
                }
            }
            __syncthreads();                   // panel reuse guard

#pragma unroll
            for (int ct = 0; ct < 2; ++ct) {
                int jc = hc0 + ct * 16 + l15;
                float bir = dec_bih[jc], bhr = dec_bhh[jc];
                float biz = dec_bih[512 + jc], bhz = dec_bhh[512 + jc];
                float bin_ = dec_bih[1024 + jc], bhn = dec_bhh[1024 + jc];
#pragma unroll
                for (int rr = 0; rr < 4; ++rr) {
                    float rv = sigf(agi[ct][rr] + bir + agh[ct][rr] + bhr);
                    float zv = sigf(agi[2 + ct][rr] + biz + agh[2 + ct][rr] + bhz);
                    float nv = tanhf(agi[4 + ct][rr] + bin_ + rv * (agh[4 + ct][rr] + bhn));
                    float v = (1.f - zv) * nv + zv * hreg[ct][rr];
                    hreg[ct][rr] = v;
                    tp[(kg * 4 + rr) * 132 + w * 32 + ct * 16 + l15] = f2bf(v);
                }
            }
            __syncthreads();
#pragma unroll
            for (int rep = 0; rep < 2; ++rep) {
                int idx = tid + rep * 256;
                int row = idx >> 5, q = idx & 31;
                unsigned long long v = *(const unsigned long long*)&tp[row * 132 + q * 4];
                st_u64_coh(&hDb[(size_t)(i & 1) * 65536 + (size_t)(R0 + row) * 512 + c * 128 + q * 4], v);
            }
            __syncthreads();
            if (tid == 0) st_i32_coh(&dfl[g2 * 32], i);
        }
    }
}

// ---------------------------------------------------------------------------
// attention for batch b: h row read as bf16 (sc1), enc slice from LDS.
// ---------------------------------------------------------------------------
__device__ void attention(int b, const unsigned short* __restrict__ hrow,
                          unsigned short* __restrict__ c_bf,
                          float* hsh, float* ssh, const unsigned short* esh)
{
    const int tid = threadIdx.x;
    if (tid < 128) {
        unsigned long long u = ld_u64_coh(&hrow[tid * 4]);
        hsh[tid * 4 + 0] = bf2f((unsigned short)(u));
        hsh[tid * 4 + 1] = bf2f((unsigned short)(u >> 16));
        hsh[tid * 4 + 2] = bf2f((unsigned short)(u >> 32));
        hsh[tid * 4 + 3] = bf2f((unsigned short)(u >> 48));
    }
    __syncthreads();
    const int wv = tid >> 6, lane = tid & 63;
    float hreg[8];
#pragma unroll
    for (int q = 0; q < 8; ++q) hreg[q] = hsh[lane * 8 + q];
#pragma unroll 4
    for (int i = wv; i < 80; i += 4) {
        bf16x8 v = *(const bf16x8*)&esh[i * 512 + lane * 8];
        float p = 0.f;
#pragma unroll
        for (int q = 0; q < 8; ++q) p += bf2f((unsigned short)v[q]) * hreg[q];
#pragma unroll
        for (int off = 32; off > 0; off >>= 1) p += __shfl_xor(p, off, 64);
        if (lane == 0) ssh[i] = tanhf(p);
    }
    __syncthreads();
    if (tid == 0) {
        float mx = -1e30f;
        for (int i = 0; i < 80; ++i) mx = fmaxf(mx, ssh[i]);
        float s = 0.f;
        for (int i = 0; i < 80; ++i) { float e = expf(ssh[i] - mx); ssh[i] = e; s += e; }
        ssh[80] = 1.0f / s;
    }
    __syncthreads();
    float acc0 = 0.f, acc1 = 0.f;
    const unsigned short* ebase = esh + tid * 2;
#pragma unroll 10
    for (int i = 0; i < 80; ++i) {
        unsigned int u = *reinterpret_cast<const unsigned int*>(&ebase[i * 512]);
        float w = ssh[i];
        acc0 += w * __builtin_bit_cast(float, u << 16);
        acc1 += w * __builtin_bit_cast(float, u & 0xffff0000u);
    }
    float inv = ssh[80];
    unsigned int packed = (unsigned int)f2bf(acc0 * inv) | ((unsigned int)f2bf(acc1 * inv) << 16);
    st_u32_coh(&c_bf[(size_t)b * 512 + tid * 2], packed);
    __syncthreads();
}

// ---------------------------------------------------------------------------
// Persistent decoder (unchanged from round 10 — passed).
// ---------------------------------------------------------------------------
__global__ __launch_bounds__(256, 1)
void decode_persist(const unsigned short* __restrict__ encout_bf,
                    const unsigned short* __restrict__ decwih_bf, const unsigned short* __restrict__ decwhh_bf,
                    const float* __restrict__ dec_bhh,
                    const unsigned short* __restrict__ outw_bf, const float* __restrict__ out_b,
                    const unsigned short* __restrict__ emb2gi, const float* __restrict__ gie,
                    const int* __restrict__ tgt,
                    const unsigned short* __restrict__ hDb,
                    unsigned short* __restrict__ hCb,
                    unsigned short* __restrict__ c_bf,
                    unsigned long long* __restrict__ pA, unsigned long long* __restrict__ pB,
                    float* __restrict__ out,
                    int* c1, int* cp, int* c2)
{
    __shared__ unsigned short esh[80 * 512];
    __shared__ float hsh[512];
    __shared__ float ssh[88];
    __shared__ unsigned long long tileq[256];
    __shared__ float sMv[256];
    __shared__ int   sIv[256];
    __shared__ float sLv[256];
    __shared__ int   sVid[32];
    unsigned short* tile16 = (unsigned short*)tileq;

    const int g = blockIdx.x;
    const int tid = threadIdx.x, w = tid >> 6, lane = tid & 63;
    const int l15 = lane & 15, kg = lane >> 4;
    float loss_acc = 0.f;

    for (int i = w; i < 80; i += 4)
        *(bf16x8*)&esh[i * 512 + lane * 8] =
            *(const bf16x8*)&encout_bf[(size_t)i * 65536 + g * 512 + lane * 8];
    __syncthreads();

    attention(g, hDb + (size_t)g * 512, c_bf, hsh, ssh, esh);
    __syncthreads();
    if (tid == 0) st_i32_coh(&c2[g * 32], 1);

    const int cg = g >> 2, rq = g & 3;
    const int rt = w >> 1, cs = w & 1;
    const int mb = rq * 32 + rt * 16;
    const int jc = cg * 32 + cs * 16 + l15;
    int wrow[3];
#pragma unroll
    for (int t = 0; t < 3; ++t) wrow[t] = t * 512 + cg * 32 + cs * 16 + l15;
    float hreg[4] = {0.f, 0.f, 0.f, 0.f};
    if (g < 64) {
#pragma unroll
        for (int rr = 0; rr < 4; ++rr)
            hreg[rr] = bf2f(ld_u16_coh(&hDb[(size_t)(mb + kg * 4 + rr) * 512 + jc]));
    }

    for (int j = 0; j < 25; ++j) {
        const unsigned short* h_in_b = (j == 0) ? hDb : hCb + (size_t)((j - 1) & 1) * 65536;
        unsigned short* h_out_b = hCb + (size_t)(j & 1) * 65536;
        unsigned long long* pAj = pA + (size_t)(j & 1) * 16384;
        unsigned long long* pBj = pB + (size_t)(j & 1) * 16384;
        const unsigned long long* pAp = pA + (size_t)((j - 1) & 1) * 16384;
        const unsigned long long* pBp = pB + (size_t)((j - 1) & 1) * 16384;

        if (g < 64) {
            if (tid < 128) spin_ge(&c2[tid * 32], j + 1);
            else if (j >= 1) spin_ge(&cp[(tid - 128) * 32], j);
            __syncthreads();
            asm volatile("" ::: "memory");

            f32x4 agi[3], agh[3];
#pragma unroll
            for (int t = 0; t < 3; ++t) { agi[t] = f32x4{0.f,0.f,0.f,0.f}; agh[t] = f32x4{0.f,0.f,0.f,0.f}; }
            bf16x8 areg[16];

            {
                const unsigned short* ap = &c_bf[(size_t)(mb + l15) * 512 + kg * 8];
                VM_FENCE;
#pragma unroll
                for (int ks = 0; ks < 16; ++ks) areg[ks] = ld_bf8_sc1(ap + ks * 32);
                VM_FENCE;
            }
#pragma unroll
            for (int ks = 0; ks < 16; ++ks)
#pragma unroll
                for (int t = 0; t < 3; ++t) {
                    bf16x8 bv = *(const bf16x8*)&decwih_bf[(size_t)wrow[t] * 1536 + 1024 + ks * 32 + kg * 8];
                    agi[t] = __builtin_amdgcn_mfma_f32_16x16x32_bf16(areg[ks], bv, agi[t], 0, 0, 0);
                }
            {
                const unsigned short* ap = &h_in_b[(size_t)(mb + l15) * 512 + kg * 8];
                VM_FENCE;
#pragma unroll
                for (int ks = 0; ks < 16; ++ks) areg[ks] = ld_bf8_sc1(ap + ks * 32);
                VM_FENCE;
            }
#pragma unroll
            for (int ks = 0; ks < 16; ++ks)
#pragma unroll
                for (int t = 0; t < 3; ++t) {
                    bf16x8 bv = *(const bf16x8*)&decwhh_bf[(size_t)wrow[t] * 512 + ks * 32 + kg * 8];
                    agh[t] = __builtin_amdgcn_mfma_f32_16x16x32_bf16(areg[ks], bv, agh[t], 0, 0, 0);
                }

            int myvid[4];
            if (j == 0) {
#pragma unroll
                for (int rr = 0; rr < 4; ++rr) myvid[rr] = BOS;
            } else {
                const int rowl = tid >> 3, seg = tid & 7;
                const int browg = rq * 32 + rowl;
                float bm = -1e30f; int bi = 0x7fffffff;
#pragma unroll
                for (int half = 0; half < 2; ++half) {
                    unsigned long long ua[8], ub[8];
#pragma unroll
                    for (int k = 0; k < 8; ++k)
                        ua[k] = ld_u64_coh(&pAp[(size_t)browg * 128 + seg * 16 + half * 8 + k]);
#pragma unroll
                    for (int k = 0; k < 8; ++k)
                        ub[k] = ld_u64_coh(&pBp[(size_t)browg * 128 + seg * 16 + half * 8 + k]);
#pragma unroll
                    for (int k = 0; k < 8; ++k) {
                        float m = __builtin_bit_cast(float, (unsigned int)ua[k]);
                        int ii = (int)(unsigned int)ub[k];
                        if (m > bm || (m == bm && ii < bi)) { bm = m; bi = ii; }
                    }
                }
                sMv[tid] = bm; sIv[tid] = bi;
                __syncthreads();
                if (seg == 0) {
                    float m = sMv[tid]; int ii = sIv[tid];
#pragma unroll
                    for (int k = 1; k < 8; ++k) {
                        float om = sMv[tid + k]; int oi = sIv[tid + k];
                        if (om > m || (om == m && oi < ii)) { m = om; ii = oi; }
                    }
                    sVid[rowl] = ii;
                }
                __syncthreads();
#pragma unroll
                for (int rr = 0; rr < 4; ++rr) myvid[rr] = sVid[rt * 16 + kg * 4 + rr];
            }

            float bhr = dec_bhh[jc], bhz = dec_bhh[512 + jc], bhn = dec_bhh[1024 + jc];
#pragma unroll
            for (int rr = 0; rr < 4; ++rr) {
                int br = mb + kg * 4 + rr;
                const float* gp = &gie[((size_t)j * 128 + br) * 1536 + jc];
                const unsigned short* ep = &emb2gi[(size_t)myvid[rr] * 1536 + jc];
                float g0 = gp[0]    + bf2f(ep[0]);
                float g1 = gp[512]  + bf2f(ep[512]);
                float g2 = gp[1024] + bf2f(ep[1024]);
                float r = sigf(g0 + agi[0][rr] + agh[0][rr] + bhr);
                float z = sigf(g1 + agi[1][rr] + agh[1][rr] + bhz);
                float n = tanhf(g2 + agi[2][rr] + r * (agh[2][rr] + bhn));
                float v = (1.f - z) * n + z * hreg[rr];
                hreg[rr] = v;
                tile16[(rt * 16 + kg * 4 + rr) * 32 + cs * 16 + l15] = f2bf(v);
            }
            __syncthreads();
            {
                size_t base = (size_t)(j & 1) * 65536 + (size_t)(rq * 32) * 512 + cg * 32;
                int row = tid >> 3, ch = tid & 7;
                st_u64_coh(&hCb[base + (size_t)row * 512 + ch * 4], tileq[tid]);
            }
            __syncthreads();
            if (tid == 0) st_i32_coh(&c1[g * 32], j + 1);
        }

        {
            if (tid < 64) spin_ge(&c1[tid * 32], j + 1);
            __syncthreads();
            asm volatile("" ::: "memory");

            const int n0 = g * 32;
            f32x4 acc[2][2];
#pragma unroll
            for (int mt = 0; mt < 2; ++mt)
#pragma unroll
                for (int nt = 0; nt < 2; ++nt) acc[mt][nt] = f32x4{0.f,0.f,0.f,0.f};
            bf16x8 ar0[16], ar1[16];
            {
                const unsigned short* p0 = &h_out_b[(size_t)(w * 32 + l15) * 512 + kg * 8];
                const unsigned short* p1 = &h_out_b[(size_t)(w * 32 + 16 + l15) * 512 + kg * 8];
                VM_FENCE;
#pragma unroll
                for (int ks = 0; ks < 16; ++ks) ar0[ks] = ld_bf8_sc1(p0 + ks * 32);
#pragma unroll
                for (int ks = 0; ks < 16; ++ks) ar1[ks] = ld_bf8_sc1(p1 + ks * 32);
                VM_FENCE;
            }
#pragma unroll
            for (int ks = 0; ks < 16; ++ks) {
                bf16x8 b0 = *(const bf16x8*)&outw_bf[(size_t)(n0 + l15) * 512 + ks * 32 + kg * 8];
                bf16x8 b1 = *(const bf16x8*)&outw_bf[(size_t)(n0 + 16 + l15) * 512 + ks * 32 + kg * 8];
                acc[0][0] = __builtin_amdgcn_mfma_f32_16x16x32_bf16(ar0[ks], b0, acc[0][0], 0, 0, 0);
                acc[0][1] = __builtin_amdgcn_mfma_f32_16x16x32_bf16(ar0[ks], b1, acc[0][1], 0, 0, 0);
                acc[1][0] = __builtin_amdgcn_mfma_f32_16x16x32_bf16(ar1[ks], b0, acc[1][0], 0, 0, 0);
                acc[1][1] = __builtin_amdgcn_mfma_f32_16x16x32_bf16(ar1[ks], b1, acc[1][1], 0, 0, 0);
            }
            float ob0 = out_b[n0 + l15], ob1 = out_b[n0 + 16 + l15];
#pragma unroll
            for (int mt = 0; mt < 2; ++mt) {
#pragma unroll
                for (int rr = 0; rr < 4; ++rr) {
                    int m = w * 32 + mt * 16 + kg * 4 + rr;
                    float v0 = acc[mt][0][rr] + ob0;
                    float v1 = acc[mt][1][rr] + ob1;
                    int tj = tgt[m * 25 + j];
                    float pm; int pi;
                    if (v0 >= v1) { pm = v0; pi = n0 + l15; }
                    else          { pm = v1; pi = n0 + 16 + l15; }
                    float pl = -1e30f;
                    if (n0 + l15 == tj)      pl = v0;
                    if (n0 + 16 + l15 == tj) pl = v1;
#pragma unroll
                    for (int off = 1; off < 16; off <<= 1) {
                        float om = __shfl_xor(pm, off, 64);
                        int   oi = __shfl_xor(pi, off, 64);
                        float ol = __shfl_xor(pl, off, 64);
                        if (om > pm || (om == pm && oi < pi)) { pm = om; pi = oi; }
                        pl = fmaxf(pl, ol);
                    }
                    float ps = expf(v0 - pm) + expf(v1 - pm);
#pragma unroll
                    for (int off = 1; off < 16; off <<= 1) ps += __shfl_xor(ps, off, 64);
                    if (l15 == 0) {
                        st_u64_coh(&pAj[(size_t)m * 128 + g], pack_ff(pm, ps));
                        st_u64_coh(&pBj[(size_t)m * 128 + g], pack_if(pi, pl));
                    }
                }
            }
            __syncthreads();
            if (tid == 0) st_i32_coh(&cp[g * 32], j + 1);
            if (j < 24) attention(g, h_out_b + (size_t)g * 512, c_bf, hsh, ssh, esh);
            __syncthreads();
            if (tid == 0) st_i32_coh(&c2[g * 32], j + 2);
        }

        if (g >= 64) {
            if (tid < 128) spin_ge(&cp[tid * 32], j + 1);
            __syncthreads();
            asm volatile("" ::: "memory");
            const int rowb = (g - 64) * 2 + (tid >> 7);
            const int t2 = tid & 127;
            unsigned long long ua = ld_u64_coh(&pAj[(size_t)rowb * 128 + t2]);
            unsigned long long ub = ld_u64_coh(&pBj[(size_t)rowb * 128 + t2]);
            float m_ = __builtin_bit_cast(float, (unsigned int)ua);
            float s_ = __builtin_bit_cast(float, (unsigned int)(ua >> 32));
            float l_ = __builtin_bit_cast(float, (unsigned int)(ub >> 32));
            sMv[tid] = m_; sLv[tid] = l_;
            __syncthreads();
            for (int st = 64; st > 0; st >>= 1) {
                if (t2 < st) {
                    sMv[tid] = fmaxf(sMv[tid], sMv[tid + st]);
                    sLv[tid] = fmaxf(sLv[tid], sLv[tid + st]);
                }
                __syncthreads();
            }
            float M = sMv[tid & 128];
            float LT = sLv[tid & 128];
            __syncthreads();
            sMv[tid] = s_ * expf(m_ - M);
            __syncthreads();
            for (int st = 64; st > 0; st >>= 1) {
                if (t2 < st) sMv[tid] += sMv[tid + st];
                __syncthreads();
            }
            if (t2 == 0) loss_acc += -(LT - (M + logf(sMv[tid])));
            __syncthreads();
        }
    }

    if (g >= 64 && (tid == 0 || tid == 128))
        atomicAdd(out, loss_acc * (1.0f / 3200.0f));
}

// fp32 -> bf16 cast (n multiple of 1024)
__global__ void cast_f2b(const float* __restrict__ in, unsigned short* __restrict__ out, int n)
{
    int i = (blockIdx.x * 256 + threadIdx.x) * 4;
    if (i < n) {
        float4 v = *reinterpret_cast<const float4*>(&in[i]);
        out[i + 0] = f2bf(v.x); out[i + 1] = f2bf(v.y);
        out[i + 2] = f2bf(v.z); out[i + 3] = f2bf(v.w);
    }
}

// ---------------------------------------------------------------------------
extern "C" void kernel_launch(void* const* d_in, const int* in_sizes, int n_in,
                              void* d_out, int out_size, void* d_ws, size_t ws_size,
                              hipStream_t stream)
{
    const float* feats   = (const float*)d_in[0];
    const float* fc_w    = (const float*)d_in[1];
    const float* fc_b    = (const float*)d_in[2];
    const float* enc_wih = (const float*)d_in[3];
    const float* enc_whh = (const float*)d_in[4];
    const float* enc_bih = (const float*)d_in[5];
    const float* enc_bhh = (const float*)d_in[6];
    const float* dec_wih = (const float*)d_in[7];
    const float* dec_whh = (const float*)d_in[8];
    const float* dec_bih = (const float*)d_in[9];
    const float* dec_bhh = (const float*)d_in[10];
    const float* out_w   = (const float*)d_in[11];
    const float* out_b   = (const float*)d_in[12];
    const float* embed   = (const float*)d_in[13];
    const int*   tgt     = (const int*)d_in[14];

    float* ws = (float*)d_ws;
    size_t off = 0;
    auto afl = [&](size_t n) { float* r = ws + off; off += n; return r; };

    unsigned short* enc_gi_bf = (unsigned short*)afl(7864320);   // [80][128][1536] bf16
    unsigned short* encout_bf = (unsigned short*)afl(3440640);   // [105][128][512] bf16
    unsigned short* xp_bf     = (unsigned short*)afl(2621440);
    unsigned short* fcw_bf    = (unsigned short*)afl(1048576);
    unsigned short* encwih_bf = (unsigned short*)afl(393216);
    unsigned short* encwhh_bf = (unsigned short*)afl(393216);
    unsigned short* decwih_bf = (unsigned short*)afl(1179648);   // 1536x1536
    unsigned short* decwhh_bf = (unsigned short*)afl(393216);
    unsigned short* outw_bf   = (unsigned short*)afl(1048576);
    unsigned short* embed_bf  = (unsigned short*)afl(1048576);   // 4096x512
    unsigned short* emb2gi    = (unsigned short*)afl(3145728);   // [4096][1536] bf16
    float* gie               = afl(4915200);                     // [25*128][1536] fp32
    float* zbias             = afl(1536);
    unsigned short* hDb       = (unsigned short*)afl(65536);     // [2][128][512] bf16
    unsigned short* hCb       = (unsigned short*)afl(65536);
    unsigned short* c_bf      = (unsigned short*)afl(32768);
    unsigned long long* pA   = (unsigned long long*)afl(65536);  // [2][128][128] u64
    unsigned long long* pB   = (unsigned long long*)afl(65536);
    int* flags               = (int*)afl(16384);

    int* efl = flags;                 // 32 lines (enc WGs)
    int* dfl = flags + 32 * 32;       // 32 lines (dec1 WGs)
    int* c1  = flags + 96 * 32;       // 64 lines
    int* cp  = flags + 160 * 32;      // 128 lines
    int* c2  = flags + 288 * 32;      // 128 lines

    hipMemsetAsync(zbias, 0, 1536 * sizeof(float), stream);
    hipMemsetAsync(flags, 0, 16384 * sizeof(int), stream);
    hipMemsetAsync(d_out, 0, sizeof(float), stream);

    cast_f2b<<<2048, 256, 0, stream>>>(fc_w, fcw_bf, 2097152);
    cast_f2b<<<768, 256, 0, stream>>>(enc_wih, encwih_bf, 786432);
    cast_f2b<<<768, 256, 0, stream>>>(enc_whh, encwhh_bf, 786432);
    cast_f2b<<<2304, 256, 0, stream>>>(dec_wih, decwih_bf, 2359296);
    cast_f2b<<<768, 256, 0, stream>>>(dec_whh, decwhh_bf, 786432);
    cast_f2b<<<2048, 256, 0, stream>>>(out_w, outw_bf, 2097152);
    cast_f2b<<<2048, 256, 0, stream>>>(embed, embed_bf, 2097152);

    // fc: xp = leaky_relu(feats @ fc_w^T + fc_b)           M=10240 K=4096 N=512
    gemm_mfma<1, 1, 1><<<dim3(4, 80), 256, 0, stream>>>(feats, 4096, fcw_bf, 4096, fc_b, xp_bf, 512, 4096);
    // enc gi (bf16): xp @ enc_wih^T + enc_bih              M=10240 K=512 N=1536
    gemm_mfma<0, 1, 0><<<dim3(12, 80), 256, 0, stream>>>(xp_bf, 512, encwih_bf, 512, enc_bih, enc_gi_bf, 1536, 512);
    // EMB2GI: embed @ dec_wih[:, :512]^T (no bias)         M=4096 K=512 N=1536
    gemm_mfma<0, 1, 0><<<dim3(12, 32), 256, 0, stream>>>(embed_bf, 512, decwih_bf, 1536, zbias, emb2gi, 1536, 512);

    recur_persist<<<64, 256, 0, stream>>>(enc_gi_bf, enc_bih, enc_bhh, encwhh_bf,
                                          decwih_bf, decwhh_bf, dec_bih, dec_bhh,
                                          encout_bf, hDb, efl, dfl);

    // GIE: enc_tail @ dec_wih[:, 512:1024]^T + dec_bih     M=3200 K=512 N=1536
    gemm_mfma<0, 0, 0><<<dim3(12, 25), 256, 0, stream>>>(encout_bf + (size_t)80 * 65536, 512,
                                                         decwih_bf + 512, 1536, dec_bih, gie, 1536, 512);

    decode_persist<<<128, 256, 0, stream>>>(encout_bf, decwih_bf, decwhh_bf,
                                            dec_bhh, outw_bf, out_b,
                                            emb2gi, gie, tgt,
                                            hDb, hCb, c_bf, pA, pB, (float*)d_out,
                                            c1, cp, c2);
}

// Round 12
// 3385.045 us; speedup vs baseline: 1.1290x; 1.1290x over previous
//
#include <hip/hip_runtime.h>
#include <hip/hip_bf16.h>

#define N_OUT 25
#define BOS   4093

typedef __attribute__((ext_vector_type(8))) short bf16x8;
typedef __attribute__((ext_vector_type(4))) float f32x4;

__device__ inline unsigned short f2bf(float f) {
    unsigned int u = __builtin_bit_cast(unsigned int, f);
    unsigned int r = (u + 0x7fffu + ((u >> 16) & 1u)) >> 16;
    return (unsigned short)r;
}
__device__ inline float bf2f(unsigned short s) {
    return __builtin_bit_cast(float, (unsigned int)s << 16);
}
__device__ inline float sigf(float x) { return 1.f / (1.f + expf(-x)); }

// ---------------------------------------------------------------------------
// Agent-scope (sc1) helpers — proven R5-R10.
// ---------------------------------------------------------------------------
__device__ __forceinline__ unsigned long long ld_u64_coh(const void* p) {
    return __hip_atomic_load((const unsigned long long*)p, __ATOMIC_RELAXED, __HIP_MEMORY_SCOPE_AGENT);
}
__device__ __forceinline__ void st_u64_coh(void* p, unsigned long long v) {
    __hip_atomic_store((unsigned long long*)p, v, __ATOMIC_RELAXED, __HIP_MEMORY_SCOPE_AGENT);
}
__device__ __forceinline__ void st_u32_coh(void* p, unsigned int v) {
    __hip_atomic_store((unsigned int*)p, v, __ATOMIC_RELAXED, __HIP_MEMORY_SCOPE_AGENT);
}
__device__ __forceinline__ unsigned short ld_u16_coh(const unsigned short* p) {
    return __hip_atomic_load(p, __ATOMIC_RELAXED, __HIP_MEMORY_SCOPE_AGENT);
}
__device__ __forceinline__ int ld_i32_coh(const int* p) {
    return __hip_atomic_load(p, __ATOMIC_RELAXED, __HIP_MEMORY_SCOPE_AGENT);
}
__device__ __forceinline__ void st_i32_coh(int* p, int v) {
    __hip_atomic_store(p, v, __ATOMIC_RELAXED, __HIP_MEMORY_SCOPE_AGENT);
}
__device__ inline unsigned long long pack_ff(float a, float b) {
    return ((unsigned long long)__builtin_bit_cast(unsigned int, b) << 32) |
           __builtin_bit_cast(unsigned int, a);
}
__device__ inline unsigned long long pack_if(int a, float b) {
    return ((unsigned long long)__builtin_bit_cast(unsigned int, b) << 32) |
           (unsigned int)a;
}
__device__ __forceinline__ void spin_ge(const int* p, int tgt)
{
    while (ld_i32_coh(p) < tgt) __builtin_amdgcn_s_sleep(1);
}

// Wide sc1 load (16B)
__device__ __forceinline__ bf16x8 ld_bf8_sc1(const unsigned short* p) {
    bf16x8 r;
    asm volatile("global_load_dwordx4 %0, %1, off sc1" : "=v"(r) : "v"(p));
    return r;
}
#define VM_FENCE do { asm volatile("s_waitcnt vmcnt(0)" ::: "memory"); \
                      __builtin_amdgcn_sched_barrier(0); } while (0)

// ---------------------------------------------------------------------------
// bf16 MFMA GEMM: C = act(A @ W^T + bias)
// ---------------------------------------------------------------------------
template<int AFP32, int OUT_BF, int ACT>
__global__ __launch_bounds__(256)
void gemm_mfma(const void* __restrict__ Ap, int lda,
               const unsigned short* __restrict__ W, int ldw,
               const float* __restrict__ bias,
               void* __restrict__ Cp, int ldc, int K)
{
    __shared__ short Abuf[128 * 32];
    __shared__ short Wbuf[128 * 32];
    const int tid  = threadIdx.x;
    const int lane = tid & 63;
    const int wave = tid >> 6;
    const int wr = wave >> 1, wc = wave & 1;
    const int l15 = lane & 15, kg = lane >> 4;
    const int m0 = blockIdx.y * 128, n0 = blockIdx.x * 128;

    const float* Af = (const float*)Ap;
    const unsigned short* Ab = (const unsigned short*)Ap;

    f32x4 acc[4][4];
#pragma unroll
    for (int i = 0; i < 4; ++i)
#pragma unroll
        for (int j = 0; j < 4; ++j) acc[i][j] = f32x4{0.f, 0.f, 0.f, 0.f};

    const bf16x8* Av = (const bf16x8*)Abuf;
    const bf16x8* Wv = (const bf16x8*)Wbuf;

    for (int k0 = 0; k0 < K; k0 += 32) {
#pragma unroll
        for (int cc = 0; cc < 2; ++cc) {
            int c = tid + cc * 256;
            int row = c >> 2, k8 = (c & 3) * 8;
            if (AFP32) {
                const float* src = &Af[(size_t)(m0 + row) * lda + k0 + k8];
                float4 v0 = *reinterpret_cast<const float4*>(src);
                float4 v1 = *reinterpret_cast<const float4*>(src + 4);
                bf16x8 s;
                s[0] = (short)f2bf(v0.x); s[1] = (short)f2bf(v0.y);
                s[2] = (short)f2bf(v0.z); s[3] = (short)f2bf(v0.w);
                s[4] = (short)f2bf(v1.x); s[5] = (short)f2bf(v1.y);
                s[6] = (short)f2bf(v1.z); s[7] = (short)f2bf(v1.w);
                *reinterpret_cast<bf16x8*>(&Abuf[row * 32 + k8]) = s;
            } else {
                *reinterpret_cast<bf16x8*>(&Abuf[row * 32 + k8]) =
                    *reinterpret_cast<const bf16x8*>(&Ab[(size_t)(m0 + row) * lda + k0 + k8]);
            }
            *reinterpret_cast<bf16x8*>(&Wbuf[row * 32 + k8]) =
                *reinterpret_cast<const bf16x8*>(&W[(size_t)(n0 + row) * ldw + k0 + k8]);
        }
        __syncthreads();
        bf16x8 a[4], b[4];
#pragma unroll
        for (int i = 0; i < 4; ++i) a[i] = Av[(wr * 64 + i * 16 + l15) * 4 + kg];
#pragma unroll
        for (int j = 0; j < 4; ++j) b[j] = Wv[(wc * 64 + j * 16 + l15) * 4 + kg];
#pragma unroll
        for (int i = 0; i < 4; ++i)
#pragma unroll
            for (int j = 0; j < 4; ++j)
                acc[i][j] = __builtin_amdgcn_mfma_f32_16x16x32_bf16(a[i], b[j], acc[i][j], 0, 0, 0);
        __syncthreads();
    }

    float* Cf = (float*)Cp;
    unsigned short* Cb = (unsigned short*)Cp;
#pragma unroll
    for (int i = 0; i < 4; ++i) {
#pragma unroll
        for (int j = 0; j < 4; ++j) {
            int n = n0 + wc * 64 + j * 16 + l15;
            float bv = bias[n];
#pragma unroll
            for (int r = 0; r < 4; ++r) {
                int m = m0 + wr * 64 + i * 16 + kg * 4 + r;
                float v = acc[i][j][r] + bv;
                if (ACT == 1) v = v > 0.f ? v : 0.01f * v;
                if (OUT_BF) Cb[(size_t)m * ldc + n] = f2bf(v);
                else        Cf[(size_t)m * ldc + n] = v;
            }
        }
    }
}

// ---------------------------------------------------------------------------
// Persistent recurrence (R10 verbatim — best measured: ~16.5 us/step).
// ---------------------------------------------------------------------------
__global__ __launch_bounds__(256, 1)
void recur_persist(const unsigned short* __restrict__ enc_gi_bf,
                   const float* __restrict__ enc_bih, const float* __restrict__ enc_bhh,
                   const unsigned short* __restrict__ encwhh_bf,
                   const unsigned short* __restrict__ decwih_bf,
                   const unsigned short* __restrict__ decwhh_bf,
                   const float* __restrict__ dec_bih, const float* __restrict__ dec_bhh,
                   unsigned short* __restrict__ encout_bf,
                   unsigned short* __restrict__ hDb,
                   int* efl, int* dfl)
{
    __shared__ unsigned long long tileq[512];
    unsigned short* tile16 = (unsigned short*)tileq;
    const int g = blockIdx.x;
    const int tid = threadIdx.x, w = tid >> 6, lane = tid & 63;
    const int l15 = lane & 15, kg = lane >> 4;

    if (g < 32) {
        const int cg = g >> 1, rh = g & 1;
        const int mb = rh * 64 + w * 16;
        int wrow[6];
#pragma unroll
        for (int ct = 0; ct < 6; ++ct) wrow[ct] = (ct >> 1) * 512 + cg * 32 + (ct & 1) * 16 + l15;
        float hreg[2][4] = {{0.f,0.f,0.f,0.f},{0.f,0.f,0.f,0.f}};

        for (int i = 0; i < 105; ++i) {
            if (i > 0) {
                if (tid < 32) spin_ge(&efl[tid * 32], i);
                __syncthreads();
                asm volatile("" ::: "memory");
            }
            bf16x8 areg[16];
            if (i > 0) {
                const unsigned short* ap = &encout_bf[(size_t)(i - 1) * 65536 + (size_t)(mb + l15) * 512 + kg * 8];
                VM_FENCE;
#pragma unroll
                for (int ks = 0; ks < 16; ++ks) areg[ks] = ld_bf8_sc1(ap + ks * 32);
                VM_FENCE;
            } else {
#pragma unroll
                for (int ks = 0; ks < 16; ++ks) areg[ks] = bf16x8{0,0,0,0,0,0,0,0};
            }
            f32x4 acc[6];
#pragma unroll
            for (int ct = 0; ct < 6; ++ct) acc[ct] = f32x4{0.f, 0.f, 0.f, 0.f};
#pragma unroll
            for (int ks = 0; ks < 16; ++ks) {
#pragma unroll
                for (int ct = 0; ct < 6; ++ct) {
                    bf16x8 bv = *(const bf16x8*)&encwhh_bf[(size_t)wrow[ct] * 512 + ks * 32 + kg * 8];
                    acc[ct] = __builtin_amdgcn_mfma_f32_16x16x32_bf16(areg[ks], bv, acc[ct], 0, 0, 0);
                }
            }
#pragma unroll
            for (int jh = 0; jh < 2; ++jh) {
                int jc = cg * 32 + jh * 16 + l15;
                float bhr = enc_bhh[jc], bhz = enc_bhh[512 + jc], bhn = enc_bhh[1024 + jc];
#pragma unroll
                for (int rr = 0; rr < 4; ++rr) {
                    int br = mb + kg * 4 + rr;
                    float gr_, gz_, gn_;
                    if (i < 80) {
                        const unsigned short* gp = enc_gi_bf + ((size_t)i * 128 + br) * 1536 + jc;
                        gr_ = bf2f(gp[0]); gz_ = bf2f(gp[512]); gn_ = bf2f(gp[1024]);
                    } else {
                        gr_ = enc_bih[jc]; gz_ = enc_bih[512 + jc]; gn_ = enc_bih[1024 + jc];
                    }
                    float r = sigf(gr_ + bhr + acc[jh][rr]);
                    float z = sigf(gz_ + bhz + acc[2 + jh][rr]);
                    float n = tanhf(gn_ + r * (acc[4 + jh][rr] + bhn));
                    float v = (1.f - z) * n + z * hreg[jh][rr];
                    hreg[jh][rr] = v;
                    tile16[(w * 16 + kg * 4 + rr) * 32 + jh * 16 + l15] = f2bf(v);
                }
            }
            __syncthreads();
            {
                size_t base = (size_t)i * 65536 + (size_t)(rh * 64) * 512 + cg * 32;
                int row = tid >> 3, ch = tid & 7;
                st_u64_coh(&encout_bf[base + (size_t)row * 512 + ch * 4], tileq[tid]);
                st_u64_coh(&encout_bf[base + (size_t)(32 + row) * 512 + ch * 4], tileq[256 + tid]);
            }
            __syncthreads();
            if (tid == 0) st_i32_coh(&efl[g * 32], i + 1);
        }
    } else {
        const int s = g - 32;
        const int cg = s >> 2, rq = s & 3;
        const int rt = w >> 1, cs = w & 1;
        const int mb = rq * 32 + rt * 16;
        int wrow[3];
#pragma unroll
        for (int t = 0; t < 3; ++t) wrow[t] = t * 512 + cg * 32 + cs * 16 + l15;
        const int jc = cg * 32 + cs * 16 + l15;
        float hreg[4] = {0.f, 0.f, 0.f, 0.f};

        for (int i = 1; i <= 80; ++i) {
            if (tid < 32) spin_ge(&efl[tid * 32], i);
            else if (tid >= 64 && tid < 128 && i >= 2) spin_ge(&dfl[(tid - 64) * 32], i - 1);
            __syncthreads();
            asm volatile("" ::: "memory");

            f32x4 agi[3], agh[3];
#pragma unroll
            for (int t = 0; t < 3; ++t) { agi[t] = f32x4{0.f,0.f,0.f,0.f}; agh[t] = f32x4{0.f,0.f,0.f,0.f}; }
            bf16x8 areg[16];
            {
                const unsigned short* ap = &encout_bf[(size_t)(i - 1) * 65536 + (size_t)(mb + l15) * 512 + kg * 8];
                VM_FENCE;
#pragma unroll
                for (int ks = 0; ks < 16; ++ks) areg[ks] = ld_bf8_sc1(ap + ks * 32);
                VM_FENCE;
            }
#pragma unroll
            for (int ks = 0; ks < 16; ++ks)
#pragma unroll
                for (int t = 0; t < 3; ++t) {
                    bf16x8 bv = *(const bf16x8*)&decwih_bf[(size_t)wrow[t] * 1536 + 1024 + ks * 32 + kg * 8];
                    agi[t] = __builtin_amdgcn_mfma_f32_16x16x32_bf16(areg[ks], bv, agi[t], 0, 0, 0);
                }
            if (i >= 2) {
                const unsigned short* ap = &hDb[(size_t)((i - 1) & 1) * 65536 + (size_t)(mb + l15) * 512 + kg * 8];
                VM_FENCE;
#pragma unroll
                for (int ks = 0; ks < 16; ++ks) areg[ks] = ld_bf8_sc1(ap + ks * 32);
                VM_FENCE;
            } else {
#pragma unroll
                for (int ks = 0; ks < 16; ++ks) areg[ks] = bf16x8{0,0,0,0,0,0,0,0};
            }
#pragma unroll
            for (int ks = 0; ks < 16; ++ks)
#pragma unroll
                for (int t = 0; t < 3; ++t) {
                    bf16x8 bv = *(const bf16x8*)&decwhh_bf[(size_t)wrow[t] * 512 + ks * 32 + kg * 8];
                    agh[t] = __builtin_amdgcn_mfma_f32_16x16x32_bf16(areg[ks], bv, agh[t], 0, 0, 0);
                }
            float bir = dec_bih[jc], bhr = dec_bhh[jc];
            float biz = dec_bih[512 + jc], bhz = dec_bhh[512 + jc];
            float bin_ = dec_bih[1024 + jc], bhn = dec_bhh[1024 + jc];
#pragma unroll
            for (int rr = 0; rr < 4; ++rr) {
                float r = sigf(agi[0][rr] + bir + agh[0][rr] + bhr);
                float z = sigf(agi[1][rr] + biz + agh[1][rr] + bhz);
                float n = tanhf(agi[2][rr] + bin_ + r * (agh[2][rr] + bhn));
                float v = (1.f - z) * n + z * hreg[rr];
                hreg[rr] = v;
                tile16[(rt * 16 + kg * 4 + rr) * 32 + cs * 16 + l15] = f2bf(v);
            }
            __syncthreads();
            {
                size_t base = (size_t)(i & 1) * 65536 + (size_t)(rq * 32) * 512 + cg * 32;
                int row = tid >> 3, ch = tid & 7;
                st_u64_coh(&hDb[base + (size_t)row * 512 + ch * 4], tileq[tid]);
            }
            __syncthreads();
            if (tid == 0) st_i32_coh(&dfl[s * 32], i);
        }
    }
}

// ---------------------------------------------------------------------------
// attention for batch b: h row read as bf16 (sc1), enc slice from LDS.
// ---------------------------------------------------------------------------
__device__ void attention(int b, const unsigned short* __restrict__ hrow,
                          unsigned short* __restrict__ c_bf,
                          float* hsh, float* ssh, const unsigned short* esh)
{
    const int tid = threadIdx.x;
    if (tid < 128) {
        unsigned long long u = ld_u64_coh(&hrow[tid * 4]);
        hsh[tid * 4 + 0] = bf2f((unsigned short)(u));
        hsh[tid * 4 + 1] = bf2f((unsigned short)(u >> 16));
        hsh[tid * 4 + 2] = bf2f((unsigned short)(u >> 32));
        hsh[tid * 4 + 3] = bf2f((unsigned short)(u >> 48));
    }
    __syncthreads();
    const int wv = tid >> 6, lane = tid & 63;
    float hreg[8];
#pragma unroll
    for (int q = 0; q < 8; ++q) hreg[q] = hsh[lane * 8 + q];
#pragma unroll 4
    for (int i = wv; i < 80; i += 4) {
        bf16x8 v = *(const bf16x8*)&esh[i * 512 + lane * 8];
        float p = 0.f;
#pragma unroll
        for (int q = 0; q < 8; ++q) p += bf2f((unsigned short)v[q]) * hreg[q];
#pragma unroll
        for (int off = 32; off > 0; off >>= 1) p += __shfl_xor(p, off, 64);
        if (lane == 0) ssh[i] = tanhf(p);
    }
    __syncthreads();
    if (tid == 0) {
        float mx = -1e30f;
        for (int i = 0; i < 80; ++i) mx = fmaxf(mx, ssh[i]);
        float s = 0.f;
        for (int i = 0; i < 80; ++i) { float e = expf(ssh[i] - mx); ssh[i] = e; s += e; }
        ssh[80] = 1.0f / s;
    }
    __syncthreads();
    float acc0 = 0.f, acc1 = 0.f;
    const unsigned short* ebase = esh + tid * 2;
#pragma unroll 10
    for (int i = 0; i < 80; ++i) {
        unsigned int u = *reinterpret_cast<const unsigned int*>(&ebase[i * 512]);
        float w = ssh[i];
        acc0 += w * __builtin_bit_cast(float, u << 16);
        acc1 += w * __builtin_bit_cast(float, u & 0xffff0000u);
    }
    float inv = ssh[80];
    unsigned int packed = (unsigned int)f2bf(acc0 * inv) | ((unsigned int)f2bf(acc1 * inv) << 16);
    st_u32_coh(&c_bf[(size_t)b * 512 + tid * 2], packed);
    __syncthreads();
}

// ---------------------------------------------------------------------------
// Persistent decoder: attention FIRST in P2 (c2 posted early, logits off the
// critical path); P1's cp wait moved to just before the argmax combine.
// ---------------------------------------------------------------------------
__global__ __launch_bounds__(256, 1)
void decode_persist(const unsigned short* __restrict__ encout_bf,
                    const unsigned short* __restrict__ decwih_bf, const unsigned short* __restrict__ decwhh_bf,
                    const float* __restrict__ dec_bhh,
                    const unsigned short* __restrict__ outw_bf, const float* __restrict__ out_b,
                    const unsigned short* __restrict__ emb2gi, const float* __restrict__ gie,
                    const int* __restrict__ tgt,
                    const unsigned short* __restrict__ hDb,
                    unsigned short* __restrict__ hCb,
                    unsigned short* __restrict__ c_bf,
                    unsigned long long* __restrict__ pA, unsigned long long* __restrict__ pB,
                    float* __restrict__ out,
                    int* c1, int* cp, int* c2)
{
    __shared__ unsigned short esh[80 * 512];
    __shared__ float hsh[512];
    __shared__ float ssh[88];
    __shared__ unsigned long long tileq[256];
    __shared__ float sMv[256];
    __shared__ int   sIv[256];
    __shared__ float sLv[256];
    __shared__ int   sVid[32];
    unsigned short* tile16 = (unsigned short*)tileq;

    const int g = blockIdx.x;
    const int tid = threadIdx.x, w = tid >> 6, lane = tid & 63;
    const int l15 = lane & 15, kg = lane >> 4;
    float loss_acc = 0.f;

    for (int i = w; i < 80; i += 4)
        *(bf16x8*)&esh[i * 512 + lane * 8] =
            *(const bf16x8*)&encout_bf[(size_t)i * 65536 + g * 512 + lane * 8];
    __syncthreads();

    attention(g, hDb + (size_t)g * 512, c_bf, hsh, ssh, esh);
    __syncthreads();
    if (tid == 0) st_i32_coh(&c2[g * 32], 1);

    const int cg = g >> 2, rq = g & 3;
    const int rt = w >> 1, cs = w & 1;
    const int mb = rq * 32 + rt * 16;
    const int jc = cg * 32 + cs * 16 + l15;
    int wrow[3];
#pragma unroll
    for (int t = 0; t < 3; ++t) wrow[t] = t * 512 + cg * 32 + cs * 16 + l15;
    float hreg[4] = {0.f, 0.f, 0.f, 0.f};
    if (g < 64) {
#pragma unroll
        for (int rr = 0; rr < 4; ++rr)
            hreg[rr] = bf2f(ld_u16_coh(&hDb[(size_t)(mb + kg * 4 + rr) * 512 + jc]));
    }

    for (int j = 0; j < 25; ++j) {
        unsigned short* h_out_b = hCb + (size_t)(j & 1) * 65536;
        unsigned long long* pAj = pA + (size_t)(j & 1) * 16384;
        unsigned long long* pBj = pB + (size_t)(j & 1) * 16384;
        const unsigned long long* pAp = pA + (size_t)((j - 1) & 1) * 16384;
        const unsigned long long* pBp = pB + (size_t)((j - 1) & 1) * 16384;

        // ---------------- P1 (WGs 0..63) ----------------
        if (g < 64) {
            const unsigned short* h_in_b = (j == 0) ? hDb : hCb + (size_t)((j - 1) & 1) * 65536;
            if (tid < 128) spin_ge(&c2[tid * 32], j + 1);
            __syncthreads();
            asm volatile("" ::: "memory");

            f32x4 agi[3], agh[3];
#pragma unroll
            for (int t = 0; t < 3; ++t) { agi[t] = f32x4{0.f,0.f,0.f,0.f}; agh[t] = f32x4{0.f,0.f,0.f,0.f}; }
            bf16x8 areg[16];

            // c-term
            {
                const unsigned short* ap = &c_bf[(size_t)(mb + l15) * 512 + kg * 8];
                VM_FENCE;
#pragma unroll
                for (int ks = 0; ks < 16; ++ks) areg[ks] = ld_bf8_sc1(ap + ks * 32);
                VM_FENCE;
            }
#pragma unroll
            for (int ks = 0; ks < 16; ++ks)
#pragma unroll
                for (int t = 0; t < 3; ++t) {
                    bf16x8 bv = *(const bf16x8*)&decwih_bf[(size_t)wrow[t] * 1536 + 1024 + ks * 32 + kg * 8];
                    agi[t] = __builtin_amdgcn_mfma_f32_16x16x32_bf16(areg[ks], bv, agi[t], 0, 0, 0);
                }
            // gh
            {
                const unsigned short* ap = &h_in_b[(size_t)(mb + l15) * 512 + kg * 8];
                VM_FENCE;
#pragma unroll
                for (int ks = 0; ks < 16; ++ks) areg[ks] = ld_bf8_sc1(ap + ks * 32);
                VM_FENCE;
            }
#pragma unroll
            for (int ks = 0; ks < 16; ++ks)
#pragma unroll
                for (int t = 0; t < 3; ++t) {
                    bf16x8 bv = *(const bf16x8*)&decwhh_bf[(size_t)wrow[t] * 512 + ks * 32 + kg * 8];
                    agh[t] = __builtin_amdgcn_mfma_f32_16x16x32_bf16(areg[ks], bv, agh[t], 0, 0, 0);
                }

            // wait partials of step j-1 ONLY NOW (overlapped with MFMA above)
            int myvid[4];
            if (j == 0) {
#pragma unroll
                for (int rr = 0; rr < 4; ++rr) myvid[rr] = BOS;
            } else {
                if (tid < 128) spin_ge(&cp[tid * 32], j);
                __syncthreads();
                asm volatile("" ::: "memory");
                const int rowl = tid >> 3, seg = tid & 7;
                const int browg = rq * 32 + rowl;
                float bm = -1e30f; int bi = 0x7fffffff;
#pragma unroll
                for (int half = 0; half < 2; ++half) {
                    unsigned long long ua[8], ub[8];
#pragma unroll
                    for (int k = 0; k < 8; ++k)
                        ua[k] = ld_u64_coh(&pAp[(size_t)browg * 128 + seg * 16 + half * 8 + k]);
#pragma unroll
                    for (int k = 0; k < 8; ++k)
                        ub[k] = ld_u64_coh(&pBp[(size_t)browg * 128 + seg * 16 + half * 8 + k]);
#pragma unroll
                    for (int k = 0; k < 8; ++k) {
                        float m = __builtin_bit_cast(float, (unsigned int)ua[k]);
                        int ii = (int)(unsigned int)ub[k];
                        if (m > bm || (m == bm && ii < bi)) { bm = m; bi = ii; }
                    }
                }
                sMv[tid] = bm; sIv[tid] = bi;
                __syncthreads();
                if (seg == 0) {
                    float m = sMv[tid]; int ii = sIv[tid];
#pragma unroll
                    for (int k = 1; k < 8; ++k) {
                        float om = sMv[tid + k]; int oi = sIv[tid + k];
                        if (om > m || (om == m && oi < ii)) { m = om; ii = oi; }
                    }
                    sVid[rowl] = ii;
                }
                __syncthreads();
#pragma unroll
                for (int rr = 0; rr < 4; ++rr) myvid[rr] = sVid[rt * 16 + kg * 4 + rr];
            }

            float bhr = dec_bhh[jc], bhz = dec_bhh[512 + jc], bhn = dec_bhh[1024 + jc];
#pragma unroll
            for (int rr = 0; rr < 4; ++rr) {
                int br = mb + kg * 4 + rr;
                const float* gp = &gie[((size_t)j * 128 + br) * 1536 + jc];
                const unsigned short* ep = &emb2gi[(size_t)myvid[rr] * 1536 + jc];
                float g0 = gp[0]    + bf2f(ep[0]);
                float g1 = gp[512]  + bf2f(ep[512]);
                float g2 = gp[1024] + bf2f(ep[1024]);
                float r = sigf(g0 + agi[0][rr] + agh[0][rr] + bhr);
                float z = sigf(g1 + agi[1][rr] + agh[1][rr] + bhz);
                float n = tanhf(g2 + agi[2][rr] + r * (agh[2][rr] + bhn));
                float v = (1.f - z) * n + z * hreg[rr];
                hreg[rr] = v;
                tile16[(rt * 16 + kg * 4 + rr) * 32 + cs * 16 + l15] = f2bf(v);
            }
            __syncthreads();
            {
                size_t base = (size_t)(j & 1) * 65536 + (size_t)(rq * 32) * 512 + cg * 32;
                int row = tid >> 3, ch = tid & 7;
                st_u64_coh(&hCb[base + (size_t)row * 512 + ch * 4], tileq[tid]);
            }
            __syncthreads();
            if (tid == 0) st_i32_coh(&c1[g * 32], j + 1);
        }

        // ---------------- P2 (all WGs): attention first, then logits -------
        {
            if (tid < 64) spin_ge(&c1[tid * 32], j + 1);
            __syncthreads();
            asm volatile("" ::: "memory");

            // attention_{j+1} FIRST -> post c2 (critical path for next P1)
            if (j < 24) attention(g, h_out_b + (size_t)g * 512, c_bf, hsh, ssh, esh);
            __syncthreads();
            if (tid == 0) st_i32_coh(&c2[g * 32], j + 2);

            // logits partials (off critical path; gates only P1's combine)
            const int n0 = g * 32;
            f32x4 acc[2][2];
#pragma unroll
            for (int mt = 0; mt < 2; ++mt)
#pragma unroll
                for (int nt = 0; nt < 2; ++nt) acc[mt][nt] = f32x4{0.f,0.f,0.f,0.f};
            bf16x8 ar0[16], ar1[16];
            {
                const unsigned short* p0 = &h_out_b[(size_t)(w * 32 + l15) * 512 + kg * 8];
                const unsigned short* p1 = &h_out_b[(size_t)(w * 32 + 16 + l15) * 512 + kg * 8];
                VM_FENCE;
#pragma unroll
                for (int ks = 0; ks < 16; ++ks) ar0[ks] = ld_bf8_sc1(p0 + ks * 32);
#pragma unroll
                for (int ks = 0; ks < 16; ++ks) ar1[ks] = ld_bf8_sc1(p1 + ks * 32);
                VM_FENCE;
            }
#pragma unroll
            for (int ks = 0; ks < 16; ++ks) {
                bf16x8 b0 = *(const bf16x8*)&outw_bf[(size_t)(n0 + l15) * 512 + ks * 32 + kg * 8];
                bf16x8 b1 = *(const bf16x8*)&outw_bf[(size_t)(n0 + 16 + l15) * 512 + ks * 32 + kg * 8];
                acc[0][0] = __builtin_amdgcn_mfma_f32_16x16x32_bf16(ar0[ks], b0, acc[0][0], 0, 0, 0);
                acc[0][1] = __builtin_amdgcn_mfma_f32_16x16x32_bf16(ar0[ks], b1, acc[0][1], 0, 0, 0);
                acc[1][0] = __builtin_amdgcn_mfma_f32_16x16x32_bf16(ar1[ks], b0, acc[1][0], 0, 0, 0);
                acc[1][1] = __builtin_amdgcn_mfma_f32_16x16x32_bf16(ar1[ks], b1, acc[1][1], 0, 0, 0);
            }
            float ob0 = out_b[n0 + l15], ob1 = out_b[n0 + 16 + l15];
#pragma unroll
            for (int mt = 0; mt < 2; ++mt) {
#pragma unroll
                for (int rr = 0; rr < 4; ++rr) {
                    int m = w * 32 + mt * 16 + kg * 4 + rr;
                    float v0 = acc[mt][0][rr] + ob0;
                    float v1 = acc[mt][1][rr] + ob1;
                    int tj = tgt[m * 25 + j];
                    float pm; int pi;
                    if (v0 >= v1) { pm = v0; pi = n0 + l15; }
                    else          { pm = v1; pi = n0 + 16 + l15; }
                    float pl = -1e30f;
                    if (n0 + l15 == tj)      pl = v0;
                    if (n0 + 16 + l15 == tj) pl = v1;
#pragma unroll
                    for (int off = 1; off < 16; off <<= 1) {
                        float om = __shfl_xor(pm, off, 64);
                        int   oi = __shfl_xor(pi, off, 64);
                        float ol = __shfl_xor(pl, off, 64);
                        if (om > pm || (om == pm && oi < pi)) { pm = om; pi = oi; }
                        pl = fmaxf(pl, ol);
                    }
                    float ps = expf(v0 - pm) + expf(v1 - pm);
#pragma unroll
                    for (int off = 1; off < 16; off <<= 1) ps += __shfl_xor(ps, off, 64);
                    if (l15 == 0) {
                        st_u64_coh(&pAj[(size_t)m * 128 + g], pack_ff(pm, ps));
                        st_u64_coh(&pBj[(size_t)m * 128 + g], pack_if(pi, pl));
                    }
                }
            }
            __syncthreads();
            if (tid == 0) st_i32_coh(&cp[g * 32], j + 1);
        }

        // ---------------- P3-lite: loss (WGs 64..127) ----------------------
        if (g >= 64) {
            if (tid < 128) spin_ge(&cp[tid * 32], j + 1);
            __syncthreads();
            asm volatile("" ::: "memory");
            const int rowb = (g - 64) * 2 + (tid >> 7);
            const int t2 = tid & 127;
            unsigned long long ua = ld_u64_coh(&pAj[(size_t)rowb * 128 + t2]);
            unsigned long long ub = ld_u64_coh(&pBj[(size_t)rowb * 128 + t2]);
            float m_ = __builtin_bit_cast(float, (unsigned int)ua);
            float s_ = __builtin_bit_cast(float, (unsigned int)(ua >> 32));
            float l_ = __builtin_bit_cast(float, (unsigned int)(ub >> 32));
            sMv[tid] = m_; sLv[tid] = l_;
            __syncthreads();
            for (int st = 64; st > 0; st >>= 1) {
                if (t2 < st) {
                    sMv[tid] = fmaxf(sMv[tid], sMv[tid + st]);
                    sLv[tid] = fmaxf(sLv[tid], sLv[tid + st]);
                }
                __syncthreads();
            }
            float M = sMv[tid & 128];
            float LT = sLv[tid & 128];
            __syncthreads();
            sMv[tid] = s_ * expf(m_ - M);
            __syncthreads();
            for (int st = 64; st > 0; st >>= 1) {
                if (t2 < st) sMv[tid] += sMv[tid + st];
                __syncthreads();
            }
            if (t2 == 0) loss_acc += -(LT - (M + logf(sMv[tid])));
            __syncthreads();
        }
    }

    if (g >= 64 && (tid == 0 || tid == 128))
        atomicAdd(out, loss_acc * (1.0f / 3200.0f));
}

// ---------------------------------------------------------------------------
// Fused cast of all 7 fp32 weight arrays -> bf16 (one launch).
// ---------------------------------------------------------------------------
__global__ __launch_bounds__(256)
void cast_all(const float* __restrict__ fc_w, const float* __restrict__ enc_wih,
              const float* __restrict__ enc_whh, const float* __restrict__ dec_wih,
              const float* __restrict__ dec_whh, const float* __restrict__ out_w,
              const float* __restrict__ embed,
              unsigned short* __restrict__ d_fcw, unsigned short* __restrict__ d_encwih,
              unsigned short* __restrict__ d_encwhh, unsigned short* __restrict__ d_decwih,
              unsigned short* __restrict__ d_decwhh, unsigned short* __restrict__ d_outw,
              unsigned short* __restrict__ d_embed)
{
    long i = (long)(blockIdx.x * 256 + threadIdx.x) * 4;
    const float* s; unsigned short* d; long off;
    if      (i <  2097152) { s = fc_w;    d = d_fcw;    off = 0; }
    else if (i <  2883584) { s = enc_wih; d = d_encwih; off = 2097152; }
    else if (i <  3670016) { s = enc_whh; d = d_encwhh; off = 2883584; }
    else if (i <  6029312) { s = dec_wih; d = d_decwih; off = 3670016; }
    else if (i <  6815744) { s = dec_whh; d = d_decwhh; off = 6029312; }
    else if (i <  8912896) { s = out_w;   d = d_outw;   off = 6815744; }
    else if (i < 11010048) { s = embed;   d = d_embed;  off = 8912896; }
    else return;
    i -= off;
    float4 v = *reinterpret_cast<const float4*>(&s[i]);
    d[i + 0] = f2bf(v.x); d[i + 1] = f2bf(v.y);
    d[i + 2] = f2bf(v.z); d[i + 3] = f2bf(v.w);
}

// ---------------------------------------------------------------------------
extern "C" void kernel_launch(void* const* d_in, const int* in_sizes, int n_in,
                              void* d_out, int out_size, void* d_ws, size_t ws_size,
                              hipStream_t stream)
{
    const float* feats   = (const float*)d_in[0];
    const float* fc_w    = (const float*)d_in[1];
    const float* fc_b    = (const float*)d_in[2];
    const float* enc_wih = (const float*)d_in[3];
    const float* enc_whh = (const float*)d_in[4];
    const float* enc_bih = (const float*)d_in[5];
    const float* enc_bhh = (const float*)d_in[6];
    const float* dec_wih = (const float*)d_in[7];
    const float* dec_whh = (const float*)d_in[8];
    const float* dec_bih = (const float*)d_in[9];
    const float* dec_bhh = (const float*)d_in[10];
    const float* out_w   = (const float*)d_in[11];
    const float* out_b   = (const float*)d_in[12];
    const float* embed   = (const float*)d_in[13];
    const int*   tgt     = (const int*)d_in[14];

    float* ws = (float*)d_ws;
    size_t off = 0;
    auto afl = [&](size_t n) { float* r = ws + off; off += n; return r; };

    unsigned short* enc_gi_bf = (unsigned short*)afl(7864320);   // [80][128][1536] bf16
    unsigned short* encout_bf = (unsigned short*)afl(3440640);   // [105][128][512] bf16
    unsigned short* xp_bf     = (unsigned short*)afl(2621440);
    unsigned short* fcw_bf    = (unsigned short*)afl(1048576);
    unsigned short* encwih_bf = (unsigned short*)afl(393216);
    unsigned short* encwhh_bf = (unsigned short*)afl(393216);
    unsigned short* decwih_bf = (unsigned short*)afl(1179648);   // 1536x1536
    unsigned short* decwhh_bf = (unsigned short*)afl(393216);
    unsigned short* outw_bf   = (unsigned short*)afl(1048576);
    unsigned short* embed_bf  = (unsigned short*)afl(1048576);   // 4096x512
    unsigned short* emb2gi    = (unsigned short*)afl(3145728);   // [4096][1536] bf16
    float* gie               = afl(4915200);                     // [25*128][1536] fp32
    float* zbias             = afl(1536);
    unsigned short* hDb       = (unsigned short*)afl(65536);     // [2][128][512] bf16
    unsigned short* hCb       = (unsigned short*)afl(65536);
    unsigned short* c_bf      = (unsigned short*)afl(32768);
    unsigned long long* pA   = (unsigned long long*)afl(65536);  // [2][128][128] u64
    unsigned long long* pB   = (unsigned long long*)afl(65536);
    int* flags               = (int*)afl(16384);

    int* efl = flags;                 // 32 lines
    int* dfl = flags + 32 * 32;       // 64 lines
    int* c1  = flags + 96 * 32;       // 64 lines
    int* cp  = flags + 160 * 32;      // 128 lines
    int* c2  = flags + 288 * 32;      // 128 lines

    hipMemsetAsync(zbias, 0, 1536 * sizeof(float), stream);
    hipMemsetAsync(flags, 0, 16384 * sizeof(int), stream);
    hipMemsetAsync(d_out, 0, sizeof(float), stream);

    cast_all<<<10752, 256, 0, stream>>>(fc_w, enc_wih, enc_whh, dec_wih, dec_whh, out_w, embed,
                                        fcw_bf, encwih_bf, encwhh_bf, decwih_bf, decwhh_bf,
                                        outw_bf, embed_bf);

    // fc: xp = leaky_relu(feats @ fc_w^T + fc_b)           M=10240 K=4096 N=512
    gemm_mfma<1, 1, 1><<<dim3(4, 80), 256, 0, stream>>>(feats, 4096, fcw_bf, 4096, fc_b, xp_bf, 512, 4096);
    // enc gi (bf16): xp @ enc_wih^T + enc_bih              M=10240 K=512 N=1536
    gemm_mfma<0, 1, 0><<<dim3(12, 80), 256, 0, stream>>>(xp_bf, 512, encwih_bf, 512, enc_bih, enc_gi_bf, 1536, 512);
    // EMB2GI: embed @ dec_wih[:, :512]^T (no bias)         M=4096 K=512 N=1536
    gemm_mfma<0, 1, 0><<<dim3(12, 32), 256, 0, stream>>>(embed_bf, 512, decwih_bf, 1536, zbias, emb2gi, 1536, 512);

    recur_persist<<<96, 256, 0, stream>>>(enc_gi_bf, enc_bih, enc_bhh, encwhh_bf,
                                          decwih_bf, decwhh_bf, dec_bih, dec_bhh,
                                          encout_bf, hDb, efl, dfl);

    // GIE: enc_tail @ dec_wih[:, 512:1024]^T + dec_bih     M=3200 K=512 N=1536
    gemm_mfma<0, 0, 0><<<dim3(12, 25), 256, 0, stream>>>(encout_bf + (size_t)80 * 65536, 512,
                                                         decwih_bf + 512, 1536, dec_bih, gie, 1536, 512);

    decode_persist<<<128, 256, 0, stream>>>(encout_bf, decwih_bf, decwhh_bf,
                                            dec_bhh, outw_bf, out_b,
                                            emb2gi, gie, tgt,
                                            hDb, hCb, c_bf, pA, pB, (float*)d_out,
                                            c1, cp, c2);
}